// Round 1
// baseline (2645.498 us; speedup 1.0000x reference)
//
#include <hip/hip_runtime.h>

// ---------------------------------------------------------------------------
// DFTB layer: spline eval -> rotation gather -> Coulomb -> batched 64x64
// generalized symmetric eigenproblem (Loewdin via Newton-Schulz S^{-1/2},
// fockp eigensolve via parallel cyclic Jacobi) -> energies.
//
// Key equivalences used (see analysis):
//  * Any X with X^T S X = I gives the same Eorb / rho_out as phiS; we use the
//    symmetric S^{-1/2} from Newton-Schulz (S is SPD, ||I-S|| ~ 0.45).
//  * jnp.linalg.eigh(symmetrize_input=True) => effective Fock = 0.5(H+H^T)+couMat.
//  * ener1 = sum(rho_out * H) only sees sym(H) since rho_out is symmetric.
// ---------------------------------------------------------------------------

#define NMOLC 2048
#define NSPC  500000
#define L0C   100000
#define NROTC 200000
#define NREPC 500000
#define MS 68   // LDS row stride (multiple of 4 -> float4-aligned rows)

// ---------------- K1: net_vals = A @ coeffs + b ----------------
__global__ __launch_bounds__(256) void k_netvals(const float* __restrict__ A,
                                                 const float* __restrict__ b,
                                                 const float* __restrict__ coeffs,
                                                 float* __restrict__ net){
  int gid = blockIdx.x * 256 + threadIdx.x;
  int row = gid >> 4;          // 16 lanes per row (64 floats = 16 float4)
  int l   = gid & 15;
  if (row >= NSPC) return;
  float4 c4 = reinterpret_cast<const float4*>(coeffs)[l];
  float4 a4 = reinterpret_cast<const float4*>(A)[(size_t)row * 16 + l];
  float s = a4.x*c4.x + a4.y*c4.y + a4.z*c4.z + a4.w*c4.w;
  s += __shfl_xor(s, 1, 16);
  s += __shfl_xor(s, 2, 16);
  s += __shfl_xor(s, 4, 16);
  s += __shfl_xor(s, 8, 16);
  if (l == 0) net[row] = s + b[row];
}

// ---------------- K2: rot_out = [0,1] ++ direct ++ rotated ----------------
__global__ __launch_bounds__(256) void k_rot(const float* __restrict__ net,
                                             const float* __restrict__ rot_tensor,
                                             const int* __restrict__ g_rot_direct,
                                             const int* __restrict__ g_rot,
                                             float* __restrict__ rot_out){
  int gid = blockIdx.x * 256 + threadIdx.x;
  if (gid == 0){ rot_out[0] = 0.f; rot_out[1] = 1.f; }
  if (gid < L0C){
    rot_out[2 + gid] = net[g_rot_direct[gid]];
  }
  int n = gid - L0C;
  if (n >= 0 && n < NROTC){
    float v0 = net[g_rot[3*n    ]];
    float v1 = net[g_rot[3*n + 1]];
    float v2 = net[g_rot[3*n + 2]];
    const float* R = rot_tensor + (size_t)9 * n;
    float* o = rot_out + 2 + L0C + 3*n;
    o[0] = R[0]*v0 + R[1]*v1 + R[2]*v2;
    o[1] = R[3]*v0 + R[4]*v1 + R[5]*v2;
    o[2] = R[6]*v0 + R[7]*v1 + R[8]*v2;
  }
}

// ---------------- K3: dQ, ep = G@dQ, ener2; zero erep ----------------
__global__ __launch_bounds__(256) void k_coulomb(const float* __restrict__ S,
                                                 const float* __restrict__ G,
                                                 const float* __restrict__ rho,
                                                 const float* __restrict__ qneutral,
                                                 float* __restrict__ ep_all,
                                                 float* __restrict__ ener2_a,
                                                 float* __restrict__ erep_a){
  __shared__ float sRed[256];
  __shared__ float sdQ[64];
  __shared__ float sEp[64];
  const int mol = blockIdx.x;
  const int t = threadIdx.x;
  const int i = t >> 2, q4 = t & 3;
  const float* Sm = S   + (size_t)mol * 4096;
  const float* Gm = G   + (size_t)mol * 4096;
  const float* Rm = rho + (size_t)mol * 4096;

  // GOP row sums of rho.*S  (4 threads per row, 16 elems each)
  float acc = 0.f;
  {
    const float4* S4 = reinterpret_cast<const float4*>(Sm + i*64 + q4*16);
    const float4* R4 = reinterpret_cast<const float4*>(Rm + i*64 + q4*16);
    #pragma unroll
    for (int m = 0; m < 4; ++m){
      float4 sv = S4[m], rv = R4[m];
      acc += sv.x*rv.x + sv.y*rv.y + sv.z*rv.z + sv.w*rv.w;
    }
  }
  sRed[t] = acc; __syncthreads();
  if (t < 64) sdQ[t] = qneutral[(size_t)mol*64 + t]
                       - (sRed[4*t] + sRed[4*t+1] + sRed[4*t+2] + sRed[4*t+3]);
  __syncthreads();

  // ep = G @ dQ
  float acc2 = 0.f;
  {
    const float4* G4 = reinterpret_cast<const float4*>(Gm + i*64 + q4*16);
    #pragma unroll
    for (int m = 0; m < 4; ++m){
      float4 gv = G4[m];
      int j0 = q4*16 + m*4;
      acc2 += gv.x*sdQ[j0] + gv.y*sdQ[j0+1] + gv.z*sdQ[j0+2] + gv.w*sdQ[j0+3];
    }
  }
  sRed[t] = acc2; __syncthreads();
  if (t < 64){
    float e = sRed[4*t] + sRed[4*t+1] + sRed[4*t+2] + sRed[4*t+3];
    sEp[t] = e;
    ep_all[(size_t)mol*64 + t] = e;
  }
  __syncthreads();
  if (t == 0){
    float s = 0.f;
    for (int j = 0; j < 64; ++j) s += sdQ[j] * sEp[j];
    ener2_a[mol] = 0.5f * s;
    erep_a[mol]  = 0.f;   // re-initialized every launch (K4 atomics follow)
  }
}

// ---------------- K4: Erep segment sum (sorted seg ids) ----------------
__global__ __launch_bounds__(256) void k_erep(const float* __restrict__ net,
                                              const int* __restrict__ g_rep,
                                              const int* __restrict__ seg_ids,
                                              float* __restrict__ erep_a){
  const int CH = 64;
  long tid = (long)blockIdx.x * 256 + threadIdx.x;
  long start = tid * CH;
  if (start >= NREPC) return;
  long end = start + CH; if (end > NREPC) end = NREPC;
  int cur = seg_ids[start];
  float acc = 0.f;
  for (long e = start; e < end; ++e){
    int sgid = seg_ids[e];
    if (sgid != cur){ atomicAdd(&erep_a[cur], acc); cur = sgid; acc = 0.f; }
    acc += net[g_rep[e]];
  }
  atomicAdd(&erep_a[cur], acc);
}

// ---------------- LDS matmul helpers (64x64, stride MS) ----------------
// D = alpha*A*B + diag*I, A SYMMETRIC (read A[k][r] as row k -> float4).
__device__ __forceinline__ void mm_symA(float (*__restrict__ D)[MS],
                                        const float (*__restrict__ A)[MS],
                                        const float (*__restrict__ B)[MS],
                                        float alpha, float diag, int t){
  const int r0 = (t & 15) << 2, c0 = (t >> 4) << 2;
  float acc[4][4];
  #pragma unroll
  for (int i = 0; i < 4; ++i)
    #pragma unroll
    for (int j = 0; j < 4; ++j) acc[i][j] = 0.f;
  #pragma unroll 4
  for (int k = 0; k < 64; ++k){
    float4 av = *reinterpret_cast<const float4*>(&A[k][r0]);
    float4 bv = *reinterpret_cast<const float4*>(&B[k][c0]);
    float a_[4] = {av.x, av.y, av.z, av.w};
    float b_[4] = {bv.x, bv.y, bv.z, bv.w};
    #pragma unroll
    for (int i = 0; i < 4; ++i)
      #pragma unroll
      for (int j = 0; j < 4; ++j)
        acc[i][j] += a_[i] * b_[j];
  }
  #pragma unroll
  for (int i = 0; i < 4; ++i)
    #pragma unroll
    for (int j = 0; j < 4; ++j)
      D[r0+i][c0+j] = alpha * acc[i][j] + ((r0+i) == (c0+j) ? diag : 0.f);
}

// D[r][c] = (sum_k A[k][r]*Bt[c][k]) * colScale[c]   (A symmetric; B given transposed)
__device__ __forceinline__ void mm_symA_Bt_scale(float (*__restrict__ D)[MS],
                                                 const float (*__restrict__ A)[MS],
                                                 const float (*__restrict__ Bt)[MS],
                                                 const float* __restrict__ colScale, int t){
  const int r0 = (t & 15) << 2, c0 = (t >> 4) << 2;
  float acc[4][4];
  #pragma unroll
  for (int i = 0; i < 4; ++i)
    #pragma unroll
    for (int j = 0; j < 4; ++j) acc[i][j] = 0.f;
  for (int k4 = 0; k4 < 64; k4 += 4){
    float a_[4][4], b_[4][4];
    #pragma unroll
    for (int kk = 0; kk < 4; ++kk){
      float4 av = *reinterpret_cast<const float4*>(&A[k4+kk][r0]);
      a_[kk][0] = av.x; a_[kk][1] = av.y; a_[kk][2] = av.z; a_[kk][3] = av.w;
    }
    #pragma unroll
    for (int j = 0; j < 4; ++j){
      float4 bv = *reinterpret_cast<const float4*>(&Bt[c0+j][k4]);
      b_[j][0] = bv.x; b_[j][1] = bv.y; b_[j][2] = bv.z; b_[j][3] = bv.w;
    }
    #pragma unroll
    for (int i = 0; i < 4; ++i)
      #pragma unroll
      for (int j = 0; j < 4; ++j)
        #pragma unroll
        for (int kk = 0; kk < 4; ++kk)
          acc[i][j] += a_[kk][i] * b_[j][kk];
  }
  #pragma unroll
  for (int i = 0; i < 4; ++i)
    #pragma unroll
    for (int j = 0; j < 4; ++j)
      D[r0+i][c0+j] = acc[i][j] * colScale[c0+j];
}

// partial = sum over thread tile of (O O^T)[r][c] * H[r][c]   (H gathered on the fly)
__device__ __forceinline__ float pm_dotH(const float (*__restrict__ O)[MS],
                                         const int* __restrict__ gm,
                                         const float* __restrict__ rot_out, int t){
  const int r0 = (t & 15) << 2, c0 = (t >> 4) << 2;
  float acc[4][4];
  #pragma unroll
  for (int i = 0; i < 4; ++i)
    #pragma unroll
    for (int j = 0; j < 4; ++j) acc[i][j] = 0.f;
  for (int k4 = 0; k4 < 64; k4 += 4){
    float a_[4][4], b_[4][4];
    #pragma unroll
    for (int i = 0; i < 4; ++i){
      float4 av = *reinterpret_cast<const float4*>(&O[r0+i][k4]);
      a_[i][0] = av.x; a_[i][1] = av.y; a_[i][2] = av.z; a_[i][3] = av.w;
    }
    #pragma unroll
    for (int j = 0; j < 4; ++j){
      float4 bv = *reinterpret_cast<const float4*>(&O[c0+j][k4]);
      b_[j][0] = bv.x; b_[j][1] = bv.y; b_[j][2] = bv.z; b_[j][3] = bv.w;
    }
    #pragma unroll
    for (int i = 0; i < 4; ++i)
      #pragma unroll
      for (int j = 0; j < 4; ++j)
        #pragma unroll
        for (int kk = 0; kk < 4; ++kk)
          acc[i][j] += a_[i][kk] * b_[j][kk];
  }
  float s = 0.f;
  #pragma unroll
  for (int i = 0; i < 4; ++i)
    #pragma unroll
    for (int j = 0; j < 4; ++j)
      s += acc[i][j] * rot_out[gm[(r0+i)*64 + (c0+j)]];
  return s;
}

__device__ __forceinline__ float4 f4rot(float c, float4 a, float s, float4 b){
  float4 r; r.x = c*a.x - s*b.x; r.y = c*a.y - s*b.y; r.z = c*a.z - s*b.z; r.w = c*a.w - s*b.w; return r;
}
__device__ __forceinline__ float4 f4rot2(float s, float4 a, float c, float4 b){
  float4 r; r.x = s*a.x + c*b.x; r.y = s*a.y + c*b.y; r.z = s*a.z + c*b.z; r.w = s*a.w + c*b.w; return r;
}

// ---------------- K5: per-molecule NS + Fock + Jacobi + energies ----------------
__global__ __launch_bounds__(256, 2) void k_eigen(const float* __restrict__ S,
                                                  const int* __restrict__ g_oper,
                                                  const float* __restrict__ rot_out,
                                                  const float* __restrict__ ep_all,
                                                  const float* __restrict__ ener2_a,
                                                  const float* __restrict__ erep_a,
                                                  float* __restrict__ out){
  __shared__ float M[4][64][MS];     // ~69.6 KB: 4 matrix buffers
  __shared__ float sRed[256];
  __shared__ float sEp[64], sLam[64], sOcc[64];
  __shared__ int   spp[32], sqq[32];
  __shared__ float scc[32], sss[32];
  __shared__ float sFrob2;

  const int t   = threadIdx.x;
  const int mol = blockIdx.x;
  const float* Sm = S + (size_t)mol * 4096;
  const int*   gm = g_oper + (size_t)mol * 4096;

  // init Y = S, Z = I; fetch ep
  #pragma unroll
  for (int m = 0; m < 16; ++m){
    int e = t + (m << 8);
    int i = e >> 6, j = e & 63;
    M[0][i][j] = Sm[e];
    M[1][i][j] = (i == j) ? 1.f : 0.f;
  }
  if (t < 64) sEp[t] = ep_all[(size_t)mol*64 + t];
  __syncthreads();

  // Newton-Schulz: Z -> S^{-1/2}. All iterates symmetric & commuting.
  int iY = 0, iZ = 1, iF1 = 2, iF2 = 3;
  for (int it = 0; it < 6; ++it){
    mm_symA(M[iF1], M[iZ], M[iY], -1.f, 3.f, t); __syncthreads();  // T  = 3I - Z*Y
    mm_symA(M[iF2], M[iY], M[iF1], 0.5f, 0.f, t); __syncthreads(); // Y' = 0.5*Y*T
    mm_symA(M[iY],  M[iF1], M[iZ], 0.5f, 0.f, t); __syncthreads(); // Z' = 0.5*T*Z
    int oY = iY, oZ = iZ, oF1 = iF1, oF2 = iF2;
    iY = oF2; iZ = oY; iF1 = oZ; iF2 = oF1;
  }
  // X = S^{-1/2} = M[iZ]

  // F = 0.5*(H + H^T) + couMat  (eigh symmetrizes its input)
  #pragma unroll
  for (int m = 0; m < 16; ++m){
    int e = t + (m << 8);
    int i = e >> 6, j = e & 63;
    float hij = rot_out[gm[e]];
    float hji = rot_out[gm[(j << 6) + i]];
    M[iF1][i][j] = 0.5f*(hij + hji) - 0.5f*Sm[e]*(sEp[i] + sEp[j]);
  }
  __syncthreads();
  // fockp = X * F * X
  mm_symA(M[iF2], M[iF1], M[iZ], 1.f, 0.f, t); __syncthreads();  // P1 = F*X
  mm_symA(M[iY],  M[iZ],  M[iF2], 1.f, 0.f, t); __syncthreads(); // A  = X*P1

  float (*Afk)[MS] = M[iY];
  float (*Vt)[MS]  = M[iF1];    // eigenvectors kept TRANSPOSED (row ops only)
  #pragma unroll
  for (int m = 0; m < 16; ++m){
    int e = t + (m << 8);
    int i = e >> 6, j = e & 63;
    Vt[i][j] = (i == j) ? 1.f : 0.f;
  }
  __syncthreads();

  // Parallel cyclic Jacobi: 63 rounds/sweep, 32 disjoint pairs/round.
  for (int sweep = 0; sweep < 8; ++sweep){
    float part = 0.f;
    #pragma unroll
    for (int m = 0; m < 16; ++m){
      int e = t + (m << 8);
      int i = e >> 6, j = e & 63;
      float v = Afk[i][j];
      part += (i == j) ? 0.f : v*v;
    }
    sRed[t] = part; __syncthreads();
    for (int w = 128; w > 0; w >>= 1){ if (t < w) sRed[t] += sRed[t + w]; __syncthreads(); }
    float off2 = sRed[0]; __syncthreads();
    if (sweep == 0){
      float dp = 0.f;
      if (t < 64){ float d = Afk[t][t]; dp = d*d; }
      sRed[t] = dp; __syncthreads();
      for (int w = 128; w > 0; w >>= 1){ if (t < w) sRed[t] += sRed[t + w]; __syncthreads(); }
      if (t == 0) sFrob2 = sRed[0] + off2;
      __syncthreads();
    }
    if (off2 <= 1e-13f * sFrob2) break;

    for (int r = 0; r < 63; ++r){
      if (t < 32){
        int p, q;
        if (t == 0){ p = 63; q = r; }
        else       { p = (r + t) % 63; q = (r - t + 63) % 63; }
        if (p > q){ int tmp = p; p = q; q = tmp; }
        float app = Afk[p][p], aqq = Afk[q][q], apq = Afk[p][q];
        float c = 1.f, s = 0.f;
        if (fabsf(apq) > 1e-30f){
          float tau = (aqq - app) / (2.f * apq);
          float tt  = copysignf(1.f, tau) / (fabsf(tau) + sqrtf(1.f + tau*tau));
          c = rsqrtf(1.f + tt*tt);
          s = tt * c;
        }
        spp[t] = p; sqq[t] = q; scc[t] = c; sss[t] = s;
      }
      __syncthreads();
      { // row phase: A rows p,q and Vt rows p,q (float4)
        int pr = t >> 3, j0 = (t & 7) << 3;
        int p = spp[pr], q = sqq[pr];
        float c = scc[pr], s = sss[pr];
        float4 ap0 = *(const float4*)&Afk[p][j0];
        float4 ap1 = *(const float4*)&Afk[p][j0+4];
        float4 aq0 = *(const float4*)&Afk[q][j0];
        float4 aq1 = *(const float4*)&Afk[q][j0+4];
        *(float4*)&Afk[p][j0]   = f4rot (c, ap0, s, aq0);
        *(float4*)&Afk[p][j0+4] = f4rot (c, ap1, s, aq1);
        *(float4*)&Afk[q][j0]   = f4rot2(s, ap0, c, aq0);
        *(float4*)&Afk[q][j0+4] = f4rot2(s, ap1, c, aq1);
        float4 vp0 = *(const float4*)&Vt[p][j0];
        float4 vp1 = *(const float4*)&Vt[p][j0+4];
        float4 vq0 = *(const float4*)&Vt[q][j0];
        float4 vq1 = *(const float4*)&Vt[q][j0+4];
        *(float4*)&Vt[p][j0]   = f4rot (c, vp0, s, vq0);
        *(float4*)&Vt[p][j0+4] = f4rot (c, vp1, s, vq1);
        *(float4*)&Vt[q][j0]   = f4rot2(s, vp0, c, vq0);
        *(float4*)&Vt[q][j0+4] = f4rot2(s, vp1, c, vq1);
      }
      __syncthreads();
      { // column phase: A cols p,q (conflict-light scalar)
        int pr = t & 31;
        int p = spp[pr], q = sqq[pr];
        float c = scc[pr], s = sss[pr];
        int jb = (t >> 5) << 3;
        #pragma unroll
        for (int m = 0; m < 8; ++m){
          int j = jb + m;
          float ajp = Afk[j][p], ajq = Afk[j][q];
          Afk[j][p] = c*ajp - s*ajq;
          Afk[j][q] = s*ajp + c*ajq;
        }
      }
      __syncthreads();
    }
  }

  // eigenvalues -> ranks (ascending), occupied = 32 lowest
  if (t < 64) sLam[t] = Afk[t][t];
  __syncthreads();
  if (t < 64){
    float lam = sLam[t];
    int rank = 0;
    for (int j = 0; j < 64; ++j){
      float lj = sLam[j];
      rank += (lj < lam || (lj == lam && j < t)) ? 1 : 0;
    }
    out[(size_t)mol*65 + 1 + rank] = lam;
    sOcc[t] = (rank < 32) ? 1.f : 0.f;
  }
  __syncthreads();

  // orb_filled = X * V * diag(occ)  (V = Vt^T)
  mm_symA_Bt_scale(M[iF2], M[iZ], Vt, sOcc, t);
  __syncthreads();

  // ener1 = 2 * sum((orb_occ orb_occ^T) .* H); Etot = ener1 + ener2 + Erep
  float s1 = pm_dotH(M[iF2], gm, rot_out, t);
  sRed[t] = s1; __syncthreads();
  for (int w = 128; w > 0; w >>= 1){ if (t < w) sRed[t] += sRed[t + w]; __syncthreads(); }
  if (t == 0){
    out[(size_t)mol*65] = 2.f * sRed[0] + ener2_a[mol] + erep_a[mol];
  }
}

// ---------------------------------------------------------------------------
extern "C" void kernel_launch(void* const* d_in, const int* in_sizes, int n_in,
                              void* d_out, int out_size, void* d_ws, size_t ws_size,
                              hipStream_t stream){
  (void)in_sizes; (void)n_in; (void)out_size; (void)ws_size;
  const float* A          = (const float*)d_in[0];
  const float* b          = (const float*)d_in[1];
  const float* coeffs     = (const float*)d_in[2];
  const float* rot_tensor = (const float*)d_in[3];
  const float* S          = (const float*)d_in[4];
  const float* G          = (const float*)d_in[5];
  const float* rho        = (const float*)d_in[6];
  const float* qneutral   = (const float*)d_in[7];
  // d_in[8] occ_mask: equivalent to rank<32 (cols < nocc), not needed
  const int* g_rot_direct = (const int*)d_in[9];
  const int* g_rot        = (const int*)d_in[10];
  const int* g_oper       = (const int*)d_in[11];
  const int* g_rep        = (const int*)d_in[12];
  const int* seg_ids      = (const int*)d_in[13];
  float* out = (float*)d_out;

  // workspace layout (floats): ~5.35 MB total
  float* W       = (float*)d_ws;
  float* net     = W;                    // 500000
  float* rot_out = W + 500000;           // 700002 (padded to 700004)
  float* ep_all  = W + 1200004;          // 2048*64
  float* ener2_a = W + 1331076;          // 2048
  float* erep_a  = W + 1333124;          // 2048

  k_netvals<<<(NSPC*16)/256, 256, 0, stream>>>(A, b, coeffs, net);
  k_rot<<<(L0C + NROTC + 255)/256, 256, 0, stream>>>(net, rot_tensor, g_rot_direct, g_rot, rot_out);
  k_coulomb<<<NMOLC, 256, 0, stream>>>(S, G, rho, qneutral, ep_all, ener2_a, erep_a);
  k_erep<<<((NREPC + 63)/64 + 255)/256, 256, 0, stream>>>(net, g_rep, seg_ids, erep_a);
  k_eigen<<<NMOLC, 256, 0, stream>>>(S, g_oper, rot_out, ep_all, ener2_a, erep_a, out);
}

// Round 2
// 2287.656 us; speedup vs baseline: 1.1564x; 1.1564x over previous
//
#include <hip/hip_runtime.h>

// ---------------------------------------------------------------------------
// DFTB layer, round 2.
//  K1 netvals / K2 rot / K3 coulomb / K4 erep  (unchanged, ~60us total)
//  K5 k_ns   : Newton-Schulz S^{-1/2} (4 iters, 9 matmuls) -> X in ws
//  K6 k_jac  : per-molecule ONE-WAVE kernel:
//              build F (H gather + couMat), fockp = X F X (shfl-matmuls),
//              Gershgorin shift, one-sided register Jacobi (no barriers,
//              no LDS matrices -> no bank conflicts), Eorb scatter,
//              ener1 = 2*sum(lam_occ) + 2*sum_ik ep_i O_ik (S O)_ik.
// ---------------------------------------------------------------------------

#define NMOLC 2048
#define NSPC  500000
#define L0C   100000
#define NROTC 200000
#define NREPC 500000
#define MS 68   // LDS row stride for k_ns matmul buffers

// ---------------- K1: net_vals = A @ coeffs + b ----------------
__global__ __launch_bounds__(256) void k_netvals(const float* __restrict__ A,
                                                 const float* __restrict__ b,
                                                 const float* __restrict__ coeffs,
                                                 float* __restrict__ net){
  int gid = blockIdx.x * 256 + threadIdx.x;
  int row = gid >> 4;
  int l   = gid & 15;
  if (row >= NSPC) return;
  float4 c4 = reinterpret_cast<const float4*>(coeffs)[l];
  float4 a4 = reinterpret_cast<const float4*>(A)[(size_t)row * 16 + l];
  float s = a4.x*c4.x + a4.y*c4.y + a4.z*c4.z + a4.w*c4.w;
  s += __shfl_xor(s, 1, 16);
  s += __shfl_xor(s, 2, 16);
  s += __shfl_xor(s, 4, 16);
  s += __shfl_xor(s, 8, 16);
  if (l == 0) net[row] = s + b[row];
}

// ---------------- K2: rot_out = [0,1] ++ direct ++ rotated ----------------
__global__ __launch_bounds__(256) void k_rot(const float* __restrict__ net,
                                             const float* __restrict__ rot_tensor,
                                             const int* __restrict__ g_rot_direct,
                                             const int* __restrict__ g_rot,
                                             float* __restrict__ rot_out){
  int gid = blockIdx.x * 256 + threadIdx.x;
  if (gid == 0){ rot_out[0] = 0.f; rot_out[1] = 1.f; }
  if (gid < L0C){
    rot_out[2 + gid] = net[g_rot_direct[gid]];
  }
  int n = gid - L0C;
  if (n >= 0 && n < NROTC){
    float v0 = net[g_rot[3*n    ]];
    float v1 = net[g_rot[3*n + 1]];
    float v2 = net[g_rot[3*n + 2]];
    const float* R = rot_tensor + (size_t)9 * n;
    float* o = rot_out + 2 + L0C + 3*n;
    o[0] = R[0]*v0 + R[1]*v1 + R[2]*v2;
    o[1] = R[3]*v0 + R[4]*v1 + R[5]*v2;
    o[2] = R[6]*v0 + R[7]*v1 + R[8]*v2;
  }
}

// ---------------- K3: dQ, ep = G@dQ, ener2; zero erep ----------------
__global__ __launch_bounds__(256) void k_coulomb(const float* __restrict__ S,
                                                 const float* __restrict__ G,
                                                 const float* __restrict__ rho,
                                                 const float* __restrict__ qneutral,
                                                 float* __restrict__ ep_all,
                                                 float* __restrict__ ener2_a,
                                                 float* __restrict__ erep_a){
  __shared__ float sRed[256];
  __shared__ float sdQ[64];
  __shared__ float sEp[64];
  const int mol = blockIdx.x;
  const int t = threadIdx.x;
  const int i = t >> 2, q4 = t & 3;
  const float* Sm = S   + (size_t)mol * 4096;
  const float* Gm = G   + (size_t)mol * 4096;
  const float* Rm = rho + (size_t)mol * 4096;

  float acc = 0.f;
  {
    const float4* S4 = reinterpret_cast<const float4*>(Sm + i*64 + q4*16);
    const float4* R4 = reinterpret_cast<const float4*>(Rm + i*64 + q4*16);
    #pragma unroll
    for (int m = 0; m < 4; ++m){
      float4 sv = S4[m], rv = R4[m];
      acc += sv.x*rv.x + sv.y*rv.y + sv.z*rv.z + sv.w*rv.w;
    }
  }
  sRed[t] = acc; __syncthreads();
  if (t < 64) sdQ[t] = qneutral[(size_t)mol*64 + t]
                       - (sRed[4*t] + sRed[4*t+1] + sRed[4*t+2] + sRed[4*t+3]);
  __syncthreads();

  float acc2 = 0.f;
  {
    const float4* G4 = reinterpret_cast<const float4*>(Gm + i*64 + q4*16);
    #pragma unroll
    for (int m = 0; m < 4; ++m){
      float4 gv = G4[m];
      int j0 = q4*16 + m*4;
      acc2 += gv.x*sdQ[j0] + gv.y*sdQ[j0+1] + gv.z*sdQ[j0+2] + gv.w*sdQ[j0+3];
    }
  }
  sRed[t] = acc2; __syncthreads();
  if (t < 64){
    float e = sRed[4*t] + sRed[4*t+1] + sRed[4*t+2] + sRed[4*t+3];
    sEp[t] = e;
    ep_all[(size_t)mol*64 + t] = e;
  }
  __syncthreads();
  if (t == 0){
    float s = 0.f;
    for (int j = 0; j < 64; ++j) s += sdQ[j] * sEp[j];
    ener2_a[mol] = 0.5f * s;
    erep_a[mol]  = 0.f;
  }
}

// ---------------- K4: Erep segment sum (sorted seg ids) ----------------
__global__ __launch_bounds__(256) void k_erep(const float* __restrict__ net,
                                              const int* __restrict__ g_rep,
                                              const int* __restrict__ seg_ids,
                                              float* __restrict__ erep_a){
  const int CH = 64;
  long tid = (long)blockIdx.x * 256 + threadIdx.x;
  long start = tid * CH;
  if (start >= NREPC) return;
  long end = start + CH; if (end > NREPC) end = NREPC;
  int cur = seg_ids[start];
  float acc = 0.f;
  for (long e = start; e < end; ++e){
    int sgid = seg_ids[e];
    if (sgid != cur){ atomicAdd(&erep_a[cur], acc); cur = sgid; acc = 0.f; }
    acc += net[g_rep[e]];
  }
  atomicAdd(&erep_a[cur], acc);
}

// ---------------- LDS matmul helper (64x64, stride MS), A symmetric ------
__device__ __forceinline__ void mm_symA(float (*__restrict__ D)[MS],
                                        const float (*__restrict__ A)[MS],
                                        const float (*__restrict__ B)[MS],
                                        float alpha, float diag, int t){
  const int r0 = (t & 15) << 2, c0 = (t >> 4) << 2;
  float acc[4][4];
  #pragma unroll
  for (int i = 0; i < 4; ++i)
    #pragma unroll
    for (int j = 0; j < 4; ++j) acc[i][j] = 0.f;
  #pragma unroll 4
  for (int k = 0; k < 64; ++k){
    float4 av = *reinterpret_cast<const float4*>(&A[k][r0]);
    float4 bv = *reinterpret_cast<const float4*>(&B[k][c0]);
    float a_[4] = {av.x, av.y, av.z, av.w};
    float b_[4] = {bv.x, bv.y, bv.z, bv.w};
    #pragma unroll
    for (int i = 0; i < 4; ++i)
      #pragma unroll
      for (int j = 0; j < 4; ++j)
        acc[i][j] += a_[i] * b_[j];
  }
  #pragma unroll
  for (int i = 0; i < 4; ++i)
    #pragma unroll
    for (int j = 0; j < 4; ++j)
      D[r0+i][c0+j] = alpha * acc[i][j] + ((r0+i) == (c0+j) ? diag : 0.f);
}

// ---------------- K5: Newton-Schulz -> X = S^{-1/2} (4 iters, 9 mm) ------
__global__ __launch_bounds__(256, 2) void k_ns(const float* __restrict__ S,
                                               float* __restrict__ X_all){
  __shared__ float M[4][64][MS];
  const int t   = threadIdx.x;
  const int mol = blockIdx.x;
  const float* Sm = S + (size_t)mol * 4096;

  // iter1 (algebraic): Y1 = 0.5*S*(3I-S), Z1 = 0.5*(3I-S)
  #pragma unroll
  for (int m = 0; m < 16; ++m){
    int e = t + (m << 8);
    int i = e >> 6, j = e & 63;
    float s = Sm[e];
    M[0][i][j] = s;
    M[2][i][j] = ((i == j) ? 3.f : 0.f) - s;
  }
  __syncthreads();
  mm_symA(M[3], M[0], M[2], 0.5f, 0.f, t);          // Y1
  #pragma unroll
  for (int m = 0; m < 16; ++m){
    int e = t + (m << 8);
    M[1][e >> 6][e & 63] = 0.5f * M[2][e >> 6][e & 63];  // Z1
  }
  __syncthreads();
  // iter2: Y=M[3], Z=M[1]
  mm_symA(M[0], M[1], M[3], -1.f, 3.f, t); __syncthreads();  // T
  mm_symA(M[2], M[3], M[0], 0.5f, 0.f, t); __syncthreads();  // Y2
  mm_symA(M[3], M[0], M[1], 0.5f, 0.f, t); __syncthreads();  // Z2
  // iter3: Y=M[2], Z=M[3]
  mm_symA(M[1], M[3], M[2], -1.f, 3.f, t); __syncthreads();  // T
  mm_symA(M[0], M[2], M[1], 0.5f, 0.f, t); __syncthreads();  // Y3
  mm_symA(M[2], M[1], M[3], 0.5f, 0.f, t); __syncthreads();  // Z3
  // iter4 (partial): Y=M[0], Z=M[2]
  mm_symA(M[3], M[2], M[0], -1.f, 3.f, t); __syncthreads();  // T
  mm_symA(M[1], M[3], M[2], 0.5f, 0.f, t); __syncthreads();  // X = 0.5*T*Z

  #pragma unroll
  for (int m = 0; m < 16; ++m){
    int e = t + (m << 8);
    X_all[(size_t)mol * 4096 + e] = M[1][e >> 6][e & 63];
  }
}

// ---------------- K6: one-wave fockp build + one-sided Jacobi + energy ----
__global__ __launch_bounds__(64, 2) void k_jac(const float* __restrict__ S,
                                               const float* __restrict__ X_all,
                                               const int* __restrict__ g_oper,
                                               const float* __restrict__ rot_out,
                                               const float* __restrict__ ep_all,
                                               const float* __restrict__ ener2_a,
                                               const float* __restrict__ erep_a,
                                               float* __restrict__ out){
  __shared__ float B[64 * 65];          // right-operand staging, stride 65
  const int lane = threadIdx.x;
  const int mol  = blockIdx.x;
  const float* Xm = X_all + (size_t)mol * 4096;
  const float* Sm = S     + (size_t)mol * 4096;
  const int*   gm = g_oper + (size_t)mol * 4096;

  float x[64];
  #pragma unroll
  for (int i = 0; i < 64; ++i) x[i] = Xm[i*64 + lane];   // x[i] = X[i][lane]
  float epl = ep_all[(size_t)mol*64 + lane];

  // --- stage H into LDS for transpose access, build F column in regs ---
  #pragma unroll
  for (int i = 0; i < 64; ++i) B[i*65 + lane] = rot_out[gm[i*64 + lane]];
  __syncthreads();
  float f[64];
  #pragma unroll
  for (int i = 0; i < 64; ++i){
    float hij = B[i*65 + lane];
    float hji = B[lane*65 + i];
    float epi = __shfl(epl, i);
    f[i] = 0.5f*(hij + hji) - 0.5f*Sm[i*64 + lane]*(epi + epl);
  }
  __syncthreads();

  // --- stage X, T = F*X : t[i] = sum_k F[i][k] * X[k][lane] ---
  #pragma unroll
  for (int i = 0; i < 64; ++i) B[i*65 + lane] = x[i];
  __syncthreads();
  float tt_[64];
  #pragma unroll
  for (int i = 0; i < 64; ++i) tt_[i] = 0.f;
  for (int k = 0; k < 64; ++k){
    float bk = B[k*65 + lane];
    #pragma unroll
    for (int i = 0; i < 64; ++i) tt_[i] = fmaf(__shfl(f[i], k), bk, tt_[i]);
  }
  __syncthreads();
  // --- stage T, w = X*T (= fockp col) ---
  #pragma unroll
  for (int i = 0; i < 64; ++i) B[i*65 + lane] = tt_[i];
  __syncthreads();
  float w[64];
  #pragma unroll
  for (int i = 0; i < 64; ++i) w[i] = 0.f;
  for (int k = 0; k < 64; ++k){
    float bk = B[k*65 + lane];
    #pragma unroll
    for (int i = 0; i < 64; ++i) w[i] = fmaf(__shfl(x[i], k), bk, w[i]);
  }

  // --- Gershgorin shift: mu = max_col sum |fockp| ; w += mu*I ---
  float csum = 0.f;
  #pragma unroll
  for (int i = 0; i < 64; ++i) csum += fabsf(w[i]);
  float mu = csum;
  #pragma unroll
  for (int d = 1; d < 64; d <<= 1) mu = fmaxf(mu, __shfl_xor(mu, d));
  #pragma unroll
  for (int i = 0; i < 64; ++i) w[i] += (i == lane) ? mu : 0.f;

  // --- V = I ---
  float v[64];
  #pragma unroll
  for (int i = 0; i < 64; ++i) v[i] = (i == lane) ? 1.f : 0.f;

  // --- one-sided (Hestenes) Jacobi, register resident, no barriers ---
  for (int sweep = 0; sweep < 8; ++sweep){
    unsigned long long swAny = 0ULL;
    for (int r = 0; r < 63; ++r){
      int part = (lane == 63) ? r : ((lane == r) ? 63 : ((2*r - lane + 126) % 63));
      float alpha = 0.f, gamma = 0.f;
      #pragma unroll
      for (int i = 0; i < 64; ++i){
        float pwi = __shfl(w[i], part);
        alpha = fmaf(w[i], w[i], alpha);
        gamma = fmaf(w[i], pwi, gamma);
      }
      float beta = __shfl(alpha, part);
      bool isp = lane < part;
      float ap = isp ? alpha : beta;
      float aq = isp ? beta  : alpha;
      bool rot = (gamma * gamma) > (1e-12f * ap * aq);
      unsigned long long bal = __ballot(rot);
      swAny |= bal;
      if (bal == 0ULL) continue;
      float tau = (aq - ap) / (2.f * gamma);
      float tq  = copysignf(1.f, tau) / (fabsf(tau) + sqrtf(fmaf(tau, tau, 1.f)));
      float c = rsqrtf(fmaf(tq, tq, 1.f));
      float s = tq * c;
      if (!rot){ c = 1.f; s = 0.f; }
      float bcoef = isp ? -s : s;
      #pragma unroll
      for (int i = 0; i < 64; ++i){
        float pwi = __shfl(w[i], part);
        float pvi = __shfl(v[i], part);
        w[i] = fmaf(bcoef, pwi, c * w[i]);
        v[i] = fmaf(bcoef, pvi, c * v[i]);
      }
    }
    if (swAny == 0ULL) break;
  }

  // --- eigenvalues (Rayleigh), ranks, Eorb ---
  float lw = 0.f;
  #pragma unroll
  for (int i = 0; i < 64; ++i) lw = fmaf(v[i], w[i], lw);
  float lam = lw - mu;
  int rank = 0;
  for (int k = 0; k < 64; ++k){
    float lk = __shfl(lam, k);
    rank += (lk < lam || (lk == lam && k < lane)) ? 1 : 0;
  }
  out[(size_t)mol*65 + 1 + rank] = lam;

  float occf = (rank < 32) ? 1.f : 0.f;
  float sl = occf * lam;
  #pragma unroll
  for (int d = 1; d < 64; d <<= 1) sl += __shfl_xor(sl, d);

  // --- O = X * V_occ ---
  __syncthreads();
  #pragma unroll
  for (int i = 0; i < 64; ++i) B[i*65 + lane] = v[i] * occf;
  __syncthreads();
  float o[64];
  #pragma unroll
  for (int i = 0; i < 64; ++i) o[i] = 0.f;
  for (int k = 0; k < 64; ++k){
    float bk = B[k*65 + lane];
    #pragma unroll
    for (int i = 0; i < 64; ++i) o[i] = fmaf(__shfl(x[i], k), bk, o[i]);
  }
  // --- U = S * O ---
  __syncthreads();
  #pragma unroll
  for (int i = 0; i < 64; ++i) B[i*65 + lane] = o[i];
  __syncthreads();
  float scol[64], u[64];
  #pragma unroll
  for (int i = 0; i < 64; ++i){ scol[i] = Sm[i*64 + lane]; u[i] = 0.f; }
  for (int k = 0; k < 64; ++k){
    float bk = B[k*65 + lane];
    #pragma unroll
    for (int i = 0; i < 64; ++i) u[i] = fmaf(__shfl(scol[i], k), bk, u[i]);
  }
  // --- ener1 = 2*sum(lam_occ) + 2*sum_ik ep_i O_ik U_ik ---
  float term = 0.f;
  #pragma unroll
  for (int i = 0; i < 64; ++i) term += __shfl(epl, i) * o[i] * u[i];
  #pragma unroll
  for (int d = 1; d < 64; d <<= 1) term += __shfl_xor(term, d);

  if (lane == 0){
    out[(size_t)mol*65] = 2.f*sl + 2.f*term + ener2_a[mol] + erep_a[mol];
  }
}

// ---------------------------------------------------------------------------
extern "C" void kernel_launch(void* const* d_in, const int* in_sizes, int n_in,
                              void* d_out, int out_size, void* d_ws, size_t ws_size,
                              hipStream_t stream){
  (void)in_sizes; (void)n_in; (void)out_size; (void)ws_size;
  const float* A          = (const float*)d_in[0];
  const float* b          = (const float*)d_in[1];
  const float* coeffs     = (const float*)d_in[2];
  const float* rot_tensor = (const float*)d_in[3];
  const float* S          = (const float*)d_in[4];
  const float* G          = (const float*)d_in[5];
  const float* rho        = (const float*)d_in[6];
  const float* qneutral   = (const float*)d_in[7];
  const int* g_rot_direct = (const int*)d_in[9];
  const int* g_rot        = (const int*)d_in[10];
  const int* g_oper       = (const int*)d_in[11];
  const int* g_rep        = (const int*)d_in[12];
  const int* seg_ids      = (const int*)d_in[13];
  float* out = (float*)d_out;

  // workspace layout (floats): total ~38.9 MB
  float* W       = (float*)d_ws;
  float* net     = W;                    // 500000
  float* rot_out = W + 500000;           // 700002 (padded to 700004)
  float* ep_all  = W + 1200004;          // 2048*64
  float* ener2_a = W + 1331076;          // 2048
  float* erep_a  = W + 1333124;          // 2048
  float* X_all   = W + 1335172;          // 2048*4096

  k_netvals<<<(NSPC*16)/256, 256, 0, stream>>>(A, b, coeffs, net);
  k_rot<<<(L0C + NROTC + 255)/256, 256, 0, stream>>>(net, rot_tensor, g_rot_direct, g_rot, rot_out);
  k_coulomb<<<NMOLC, 256, 0, stream>>>(S, G, rho, qneutral, ep_all, ener2_a, erep_a);
  k_erep<<<((NREPC + 63)/64 + 255)/256, 256, 0, stream>>>(net, g_rep, seg_ids, erep_a);
  k_ns<<<NMOLC, 256, 0, stream>>>(S, X_all);
  k_jac<<<NMOLC, 64, 0, stream>>>(S, X_all, g_oper, rot_out, ep_all, ener2_a, erep_a, out);
}

// Round 3
// 1126.292 us; speedup vs baseline: 2.3489x; 2.0311x over previous
//
#include <hip/hip_runtime.h>

// ---------------------------------------------------------------------------
// DFTB layer, round 3.
//  K1 netvals / K2 rot / K3 coulomb / K4 erep  (unchanged)
//  K5 k_ns  : Newton-Schulz S^{-1/2} (4 iters, 9 matmuls) -> X in ws
//  K6 k_jac : one wave per molecule. Register-budgeted design (<=128 floats
//             live + temps, no spills):
//             - F build: H gather via LDS transpose (stride 65)
//             - fockp = X F X via LDS-BROADCAST matmuls (stride 68, b128)
//             - one-sided Jacobi WITHOUT carrying V: lambda = ||w||,
//               v = w/lambda at convergence (PD after Gershgorin shift);
//               partner column cached in regs -> 65 bpermutes/round
//             - ener1 = 2*sum(lam_occ) + 2*sum_ik ep_i O_ik (S O)_ik
// ---------------------------------------------------------------------------

#define NMOLC 2048
#define NSPC  500000
#define L0C   100000
#define NROTC 200000
#define NREPC 500000
#define MS 68   // LDS row stride for k_ns matmul buffers

// ---------------- K1: net_vals = A @ coeffs + b ----------------
__global__ __launch_bounds__(256) void k_netvals(const float* __restrict__ A,
                                                 const float* __restrict__ b,
                                                 const float* __restrict__ coeffs,
                                                 float* __restrict__ net){
  int gid = blockIdx.x * 256 + threadIdx.x;
  int row = gid >> 4;
  int l   = gid & 15;
  if (row >= NSPC) return;
  float4 c4 = reinterpret_cast<const float4*>(coeffs)[l];
  float4 a4 = reinterpret_cast<const float4*>(A)[(size_t)row * 16 + l];
  float s = a4.x*c4.x + a4.y*c4.y + a4.z*c4.z + a4.w*c4.w;
  s += __shfl_xor(s, 1, 16);
  s += __shfl_xor(s, 2, 16);
  s += __shfl_xor(s, 4, 16);
  s += __shfl_xor(s, 8, 16);
  if (l == 0) net[row] = s + b[row];
}

// ---------------- K2: rot_out = [0,1] ++ direct ++ rotated ----------------
__global__ __launch_bounds__(256) void k_rot(const float* __restrict__ net,
                                             const float* __restrict__ rot_tensor,
                                             const int* __restrict__ g_rot_direct,
                                             const int* __restrict__ g_rot,
                                             float* __restrict__ rot_out){
  int gid = blockIdx.x * 256 + threadIdx.x;
  if (gid == 0){ rot_out[0] = 0.f; rot_out[1] = 1.f; }
  if (gid < L0C){
    rot_out[2 + gid] = net[g_rot_direct[gid]];
  }
  int n = gid - L0C;
  if (n >= 0 && n < NROTC){
    float v0 = net[g_rot[3*n    ]];
    float v1 = net[g_rot[3*n + 1]];
    float v2 = net[g_rot[3*n + 2]];
    const float* R = rot_tensor + (size_t)9 * n;
    float* o = rot_out + 2 + L0C + 3*n;
    o[0] = R[0]*v0 + R[1]*v1 + R[2]*v2;
    o[1] = R[3]*v0 + R[4]*v1 + R[5]*v2;
    o[2] = R[6]*v0 + R[7]*v1 + R[8]*v2;
  }
}

// ---------------- K3: dQ, ep = G@dQ, ener2; zero erep ----------------
__global__ __launch_bounds__(256) void k_coulomb(const float* __restrict__ S,
                                                 const float* __restrict__ G,
                                                 const float* __restrict__ rho,
                                                 const float* __restrict__ qneutral,
                                                 float* __restrict__ ep_all,
                                                 float* __restrict__ ener2_a,
                                                 float* __restrict__ erep_a){
  __shared__ float sRed[256];
  __shared__ float sdQ[64];
  __shared__ float sEp[64];
  const int mol = blockIdx.x;
  const int t = threadIdx.x;
  const int i = t >> 2, q4 = t & 3;
  const float* Sm = S   + (size_t)mol * 4096;
  const float* Gm = G   + (size_t)mol * 4096;
  const float* Rm = rho + (size_t)mol * 4096;

  float acc = 0.f;
  {
    const float4* S4 = reinterpret_cast<const float4*>(Sm + i*64 + q4*16);
    const float4* R4 = reinterpret_cast<const float4*>(Rm + i*64 + q4*16);
    #pragma unroll
    for (int m = 0; m < 4; ++m){
      float4 sv = S4[m], rv = R4[m];
      acc += sv.x*rv.x + sv.y*rv.y + sv.z*rv.z + sv.w*rv.w;
    }
  }
  sRed[t] = acc; __syncthreads();
  if (t < 64) sdQ[t] = qneutral[(size_t)mol*64 + t]
                       - (sRed[4*t] + sRed[4*t+1] + sRed[4*t+2] + sRed[4*t+3]);
  __syncthreads();

  float acc2 = 0.f;
  {
    const float4* G4 = reinterpret_cast<const float4*>(Gm + i*64 + q4*16);
    #pragma unroll
    for (int m = 0; m < 4; ++m){
      float4 gv = G4[m];
      int j0 = q4*16 + m*4;
      acc2 += gv.x*sdQ[j0] + gv.y*sdQ[j0+1] + gv.z*sdQ[j0+2] + gv.w*sdQ[j0+3];
    }
  }
  sRed[t] = acc2; __syncthreads();
  if (t < 64){
    float e = sRed[4*t] + sRed[4*t+1] + sRed[4*t+2] + sRed[4*t+3];
    sEp[t] = e;
    ep_all[(size_t)mol*64 + t] = e;
  }
  __syncthreads();
  if (t == 0){
    float s = 0.f;
    for (int j = 0; j < 64; ++j) s += sdQ[j] * sEp[j];
    ener2_a[mol] = 0.5f * s;
    erep_a[mol]  = 0.f;
  }
}

// ---------------- K4: Erep segment sum (sorted seg ids) ----------------
__global__ __launch_bounds__(256) void k_erep(const float* __restrict__ net,
                                              const int* __restrict__ g_rep,
                                              const int* __restrict__ seg_ids,
                                              float* __restrict__ erep_a){
  const int CH = 64;
  long tid = (long)blockIdx.x * 256 + threadIdx.x;
  long start = tid * CH;
  if (start >= NREPC) return;
  long end = start + CH; if (end > NREPC) end = NREPC;
  int cur = seg_ids[start];
  float acc = 0.f;
  for (long e = start; e < end; ++e){
    int sgid = seg_ids[e];
    if (sgid != cur){ atomicAdd(&erep_a[cur], acc); cur = sgid; acc = 0.f; }
    acc += net[g_rep[e]];
  }
  atomicAdd(&erep_a[cur], acc);
}

// ---------------- LDS matmul helper (64x64, stride MS), A symmetric ------
__device__ __forceinline__ void mm_symA(float (*__restrict__ D)[MS],
                                        const float (*__restrict__ A)[MS],
                                        const float (*__restrict__ B)[MS],
                                        float alpha, float diag, int t){
  const int r0 = (t & 15) << 2, c0 = (t >> 4) << 2;
  float acc[4][4];
  #pragma unroll
  for (int i = 0; i < 4; ++i)
    #pragma unroll
    for (int j = 0; j < 4; ++j) acc[i][j] = 0.f;
  #pragma unroll 4
  for (int k = 0; k < 64; ++k){
    float4 av = *reinterpret_cast<const float4*>(&A[k][r0]);
    float4 bv = *reinterpret_cast<const float4*>(&B[k][c0]);
    float a_[4] = {av.x, av.y, av.z, av.w};
    float b_[4] = {bv.x, bv.y, bv.z, bv.w};
    #pragma unroll
    for (int i = 0; i < 4; ++i)
      #pragma unroll
      for (int j = 0; j < 4; ++j)
        acc[i][j] += a_[i] * b_[j];
  }
  #pragma unroll
  for (int i = 0; i < 4; ++i)
    #pragma unroll
    for (int j = 0; j < 4; ++j)
      D[r0+i][c0+j] = alpha * acc[i][j] + ((r0+i) == (c0+j) ? diag : 0.f);
}

// ---------------- K5: Newton-Schulz -> X = S^{-1/2} (4 iters, 9 mm) ------
__global__ __launch_bounds__(256, 2) void k_ns(const float* __restrict__ S,
                                               float* __restrict__ X_all){
  __shared__ float M[4][64][MS];
  const int t   = threadIdx.x;
  const int mol = blockIdx.x;
  const float* Sm = S + (size_t)mol * 4096;

  #pragma unroll
  for (int m = 0; m < 16; ++m){
    int e = t + (m << 8);
    int i = e >> 6, j = e & 63;
    float s = Sm[e];
    M[0][i][j] = s;
    M[2][i][j] = ((i == j) ? 3.f : 0.f) - s;
  }
  __syncthreads();
  mm_symA(M[3], M[0], M[2], 0.5f, 0.f, t);          // Y1
  #pragma unroll
  for (int m = 0; m < 16; ++m){
    int e = t + (m << 8);
    M[1][e >> 6][e & 63] = 0.5f * M[2][e >> 6][e & 63];  // Z1
  }
  __syncthreads();
  mm_symA(M[0], M[1], M[3], -1.f, 3.f, t); __syncthreads();
  mm_symA(M[2], M[3], M[0], 0.5f, 0.f, t); __syncthreads();
  mm_symA(M[3], M[0], M[1], 0.5f, 0.f, t); __syncthreads();
  mm_symA(M[1], M[3], M[2], -1.f, 3.f, t); __syncthreads();
  mm_symA(M[0], M[2], M[1], 0.5f, 0.f, t); __syncthreads();
  mm_symA(M[2], M[1], M[3], 0.5f, 0.f, t); __syncthreads();
  mm_symA(M[3], M[2], M[0], -1.f, 3.f, t); __syncthreads();
  mm_symA(M[1], M[3], M[2], 0.5f, 0.f, t); __syncthreads();

  #pragma unroll
  for (int m = 0; m < 16; ++m){
    int e = t + (m << 8);
    X_all[(size_t)mol * 4096 + e] = M[1][e >> 6][e & 63];
  }
}

// ---------------- K6: one-wave fockp + V-free one-sided Jacobi -----------
__global__ __launch_bounds__(64, 2) void k_jac(const float* __restrict__ S,
                                               const float* __restrict__ X_all,
                                               const int* __restrict__ g_oper,
                                               const float* __restrict__ rot_out,
                                               const float* __restrict__ ep_all,
                                               const float* __restrict__ ener2_a,
                                               const float* __restrict__ erep_a,
                                               float* __restrict__ out){
  __shared__ float B[64 * 68];          // one staging buffer, reused
  const int lane = threadIdx.x;
  const int mol  = blockIdx.x;
  const float* Xm = X_all + (size_t)mol * 4096;
  const float* Sm = S     + (size_t)mol * 4096;
  const int*   gm = g_oper + (size_t)mol * 4096;
  const float  epl = ep_all[(size_t)mol*64 + lane];

  // --- H gather (stride 65: transpose read is 2-way -> free) ---
  float h[64];
  #pragma unroll
  for (int i = 0; i < 64; ++i){
    float v = rot_out[gm[i*64 + lane]];
    h[i] = v;
    B[i*65 + lane] = v;
  }
  __syncthreads();
  // F column: f[i] = 0.5(H_ij + H_ji) - 0.5 S_ij (ep_i + ep_j)
  #pragma unroll
  for (int i = 0; i < 64; ++i){
    float hji = B[lane*65 + i];
    float epi = __shfl(epl, i);
    h[i] = 0.5f*(h[i] + hji) - 0.5f*Sm[i*64 + lane]*(epi + epl);
  }
  __syncthreads();
  // stage F (stride 68, float4-aligned rows for broadcast b128 reads)
  #pragma unroll
  for (int i = 0; i < 64; ++i) B[i*68 + lane] = h[i];
  __syncthreads();

  // --- T = F*X: tt[i] = sum_k F[i][k] * x[k], F broadcast from LDS ---
  float x[64];
  #pragma unroll
  for (int i = 0; i < 64; ++i) x[i] = Xm[i*64 + lane];
  float tt[64];
  #pragma unroll
  for (int i = 0; i < 64; ++i){
    float acc = 0.f;
    #pragma unroll
    for (int k = 0; k < 64; k += 4){
      float4 fv = *reinterpret_cast<const float4*>(&B[i*68 + k]);
      acc = fmaf(fv.x, x[k], acc);   acc = fmaf(fv.y, x[k+1], acc);
      acc = fmaf(fv.z, x[k+2], acc); acc = fmaf(fv.w, x[k+3], acc);
    }
    tt[i] = acc;
  }
  __syncthreads();
  // stage X (kept resident in LDS through Jacobi for the epilogue)
  #pragma unroll
  for (int i = 0; i < 64; ++i) B[i*68 + lane] = x[i];
  __syncthreads();

  // --- w = X*T (fockp column) ---
  float w[64];
  #pragma unroll
  for (int i = 0; i < 64; ++i){
    float acc = 0.f;
    #pragma unroll
    for (int k = 0; k < 64; k += 4){
      float4 xv = *reinterpret_cast<const float4*>(&B[i*68 + k]);
      acc = fmaf(xv.x, tt[k], acc);   acc = fmaf(xv.y, tt[k+1], acc);
      acc = fmaf(xv.z, tt[k+2], acc); acc = fmaf(xv.w, tt[k+3], acc);
    }
    w[i] = acc;
  }

  // --- Gershgorin shift (PD): mu = 1.02 * max col abs-sum ---
  float csum = 0.f;
  #pragma unroll
  for (int i = 0; i < 64; ++i) csum += fabsf(w[i]);
  float mu = csum;
  #pragma unroll
  for (int d = 1; d < 64; d <<= 1) mu = fmaxf(mu, __shfl_xor(mu, d));
  mu *= 1.02f;
  #pragma unroll
  for (int i = 0; i < 64; ++i) w[i] += (i == lane) ? mu : 0.f;

  // --- one-sided Jacobi, V-free, partner column cached ---
  for (int sweep = 0; sweep < 8; ++sweep){
    float alpha = 0.f;
    #pragma unroll
    for (int i = 0; i < 64; ++i) alpha = fmaf(w[i], w[i], alpha);
    unsigned long long any = 0ULL;
    for (int r = 0; r < 63; ++r){
      int part = (lane == 63) ? r : ((lane == r) ? 63 : ((2*r - lane + 126) % 63));
      float pw[64];
      float gamma = 0.f;
      #pragma unroll
      for (int i = 0; i < 64; ++i){
        pw[i] = __shfl(w[i], part);
        gamma = fmaf(w[i], pw[i], gamma);
      }
      float beta = __shfl(alpha, part);
      bool isp = lane < part;
      float ap = isp ? alpha : beta;
      float aq = isp ? beta  : alpha;
      bool rot = (gamma * gamma) > (1e-12f * ap * aq);
      unsigned long long bal = __ballot(rot);
      any |= bal;
      if (bal == 0ULL) continue;
      float tau = (aq - ap) / (2.f * gamma);
      float tq  = copysignf(1.f, tau) / (fabsf(tau) + sqrtf(fmaf(tau, tau, 1.f)));
      float c = rsqrtf(fmaf(tq, tq, 1.f));
      float s = tq * c;
      if (!rot){ c = 1.f; s = 0.f; }
      float bcoef = isp ? -s : s;
      alpha = c*c*alpha + s*s*beta + 2.f*c*bcoef*gamma;
      #pragma unroll
      for (int i = 0; i < 64; ++i)
        w[i] = fmaf(bcoef, pw[i], c * w[i]);
    }
    if (any == 0ULL) break;
  }

  // --- lambda = ||w|| - mu; ranks; Eorb; v = w * (occ/||w||) ---
  float a2 = 0.f;
  #pragma unroll
  for (int i = 0; i < 64; ++i) a2 = fmaf(w[i], w[i], a2);
  float lamS = sqrtf(a2);
  float lam  = lamS - mu;
  int rank = 0;
  for (int k = 0; k < 64; ++k){
    float lk = __shfl(lam, k);
    rank += (lk < lam || (lk == lam && k < lane)) ? 1 : 0;
  }
  out[(size_t)mol*65 + 1 + rank] = lam;

  float occf = (rank < 32) ? 1.f : 0.f;
  float slam = occf * lam;
  #pragma unroll
  for (int d = 1; d < 64; d <<= 1) slam += __shfl_xor(slam, d);

  float scale = occf / lamS;
  #pragma unroll
  for (int i = 0; i < 64; ++i) w[i] *= scale;   // w := v_occ column

  // --- O = X * V_occ (X still staged in LDS) ---
  float o[64];
  #pragma unroll
  for (int i = 0; i < 64; ++i){
    float acc = 0.f;
    #pragma unroll
    for (int k = 0; k < 64; k += 4){
      float4 xv = *reinterpret_cast<const float4*>(&B[i*68 + k]);
      acc = fmaf(xv.x, w[k], acc);   acc = fmaf(xv.y, w[k+1], acc);
      acc = fmaf(xv.z, w[k+2], acc); acc = fmaf(xv.w, w[k+3], acc);
    }
    o[i] = acc;
  }
  // --- U = S * O  (S rows broadcast from global; L1-resident) ---
  float u[64];
  #pragma unroll
  for (int i = 0; i < 64; ++i){
    float acc = 0.f;
    #pragma unroll
    for (int k = 0; k < 64; k += 4){
      float4 sv = *reinterpret_cast<const float4*>(Sm + i*64 + k);
      acc = fmaf(sv.x, o[k], acc);   acc = fmaf(sv.y, o[k+1], acc);
      acc = fmaf(sv.z, o[k+2], acc); acc = fmaf(sv.w, o[k+3], acc);
    }
    u[i] = acc;
  }
  // --- ener1 = 2*sum(lam_occ) + 2*sum_ik ep_i O_ik U_ik ---
  float term = 0.f;
  #pragma unroll
  for (int i = 0; i < 64; ++i) term = fmaf(__shfl(epl, i), o[i]*u[i], term);
  #pragma unroll
  for (int d = 1; d < 64; d <<= 1) term += __shfl_xor(term, d);

  if (lane == 0){
    out[(size_t)mol*65] = 2.f*slam + 2.f*term + ener2_a[mol] + erep_a[mol];
  }
}

// ---------------------------------------------------------------------------
extern "C" void kernel_launch(void* const* d_in, const int* in_sizes, int n_in,
                              void* d_out, int out_size, void* d_ws, size_t ws_size,
                              hipStream_t stream){
  (void)in_sizes; (void)n_in; (void)out_size; (void)ws_size;
  const float* A          = (const float*)d_in[0];
  const float* b          = (const float*)d_in[1];
  const float* coeffs     = (const float*)d_in[2];
  const float* rot_tensor = (const float*)d_in[3];
  const float* S          = (const float*)d_in[4];
  const float* G          = (const float*)d_in[5];
  const float* rho        = (const float*)d_in[6];
  const float* qneutral   = (const float*)d_in[7];
  const int* g_rot_direct = (const int*)d_in[9];
  const int* g_rot        = (const int*)d_in[10];
  const int* g_oper       = (const int*)d_in[11];
  const int* g_rep        = (const int*)d_in[12];
  const int* seg_ids      = (const int*)d_in[13];
  float* out = (float*)d_out;

  float* W       = (float*)d_ws;
  float* net     = W;                    // 500000
  float* rot_out = W + 500000;           // 700002 (padded to 700004)
  float* ep_all  = W + 1200004;          // 2048*64
  float* ener2_a = W + 1331076;          // 2048
  float* erep_a  = W + 1333124;          // 2048
  float* X_all   = W + 1335172;          // 2048*4096

  k_netvals<<<(NSPC*16)/256, 256, 0, stream>>>(A, b, coeffs, net);
  k_rot<<<(L0C + NROTC + 255)/256, 256, 0, stream>>>(net, rot_tensor, g_rot_direct, g_rot, rot_out);
  k_coulomb<<<NMOLC, 256, 0, stream>>>(S, G, rho, qneutral, ep_all, ener2_a, erep_a);
  k_erep<<<((NREPC + 63)/64 + 255)/256, 256, 0, stream>>>(net, g_rep, seg_ids, erep_a);
  k_ns<<<NMOLC, 256, 0, stream>>>(S, X_all);
  k_jac<<<NMOLC, 64, 0, stream>>>(S, X_all, g_oper, rot_out, ep_all, ener2_a, erep_a, out);
}